// Round 2
// baseline (1082.574 us; speedup 1.0000x reference)
//
#include <hip/hip_runtime.h>
#include <hip/hip_bf16.h>

#define B_ 128
#define H_ 512
#define S_ 2048
#define ST 64          // s-tile per pass-1 block
#define NP (S_/ST)     // 32 partials per batch

typedef short  bf16x8  __attribute__((ext_vector_type(8)));
typedef float  floatx4 __attribute__((ext_vector_type(4)));
typedef short  short4v __attribute__((ext_vector_type(4)));

// 2*log2(e): tanh(x) = 1 - 2*rcp(exp2(KT*x)+1)  (saturates correctly at +-inf)
#define KT_TANH 2.8853900817779268f

__device__ __forceinline__ unsigned short f2bf(float f){
  unsigned u = __float_as_uint(f);
  unsigned r = (u + 0x7fffu + ((u >> 16) & 1u)) >> 16;   // RNE
  return (unsigned short)r;
}
__device__ __forceinline__ float bf2f(unsigned short h){
  return __uint_as_float(((unsigned)h) << 16);
}
// r = rcp(exp2(a)+1) ; tanh = 1 - 2r
__device__ __forceinline__ float tanh_r(float a){
  float e = __builtin_amdgcn_exp2f(a);
  return __builtin_amdgcn_rcpf(e + 1.f);
}
// XOR swizzle: row-stride 512 elems (no pad); 16B chunk c of row s lives at
// phys = (c & 56) | ((c ^ s) & 7). Conflict-free for row-writes, frag-reads,
// and full-row readback (bijective in c for fixed s).
__device__ __forceinline__ int swz(int s, int c){
  return (c & 56) | ((c ^ s) & 7);
}

// ---------------- k0: W_att fp32 -> bf16 ----------------
__global__ __launch_bounds__(256) void k_convW(const float* __restrict__ W,
                                               unsigned short* __restrict__ Wb){
  int i = (blockIdx.x * 256 + threadIdx.x) * 4;
  float4 v = *(const float4*)(W + i);
  short4v o;
  o[0] = (short)f2bf(v.x); o[1] = (short)f2bf(v.y);
  o[2] = (short)f2bf(v.z); o[3] = (short)f2bf(v.w);
  *(short4v*)(Wb + i) = o;
}

// ---------------- k_pass1: stage + scores GEMM + tanh.v + partial softmax ---
// grid = B*NP blocks of 512 (8 waves). Wave w owns h-rows [w*64, w*64+64).
// k-loop is 2-deep software-pipelined (A from L2, B from LDS); softmax is a
// single-wave shuffle reduce (no serial LDS loops).
__global__ __launch_bounds__(512, 4) void k_pass1(
    const float* __restrict__ hidden, const float* __restrict__ v_att,
    const unsigned short* __restrict__ Wb,
    float* __restrict__ part_m, float* __restrict__ part_z,
    float* __restrict__ part_ctx)
{
  // pctx (16 KiB fp32 cross-wave ctx reduce) aliases Bs (barrier-separated).
  union __align__(16) SMem {
    unsigned short Bs[ST * 512];   // 64 KiB, swizzled bf16 [s][k]
    float pctx[8 * H_];            // 16 KiB
  };
  __shared__ SMem sm;
  __shared__ float vatt[H_];
  __shared__ float twav[8][ST];
  __shared__ float es[ST];

  const int tid = threadIdx.x;
  const int w = tid >> 6, l = tid & 63;
  const int p = blockIdx.x & (NP - 1);
  const int b = blockIdx.x >> 5;          // NP == 32
  const int s0 = p * ST;

  vatt[tid] = v_att[tid];

  // Stage hidden[b, :, s0:s0+64] -> bf16 LDS [s][k] (swizzled).
  // Thread: row s=l, 8 chunks c = w + it*8; chunk = 8 h, stride-S gather
  // (coalesced 256B/wave per h-row). Nontemporal: keep Wb L2-hot.
  {
    const float* src0 = hidden + ((size_t)b * H_) * S_ + s0 + l;
    #pragma unroll
    for (int it = 0; it < 8; ++it){
      const int c = w + it * 8;
      const float* src = src0 + (size_t)(c * 8) * S_;
      bf16x8 pk;
      #pragma unroll
      for (int j = 0; j < 8; ++j)
        pk[j] = (short)f2bf(__builtin_nontemporal_load(src + (size_t)j * S_));
      *(bf16x8*)(&sm.Bs[l * 512 + swz(l, c) * 8]) = pk;
    }
  }

  const int quad = l >> 4, l16 = l & 15;

  // SVA = sum_h v_att[h]; full-wave xor reduce in wave 0 -> register (all lanes)
  float sva = 0.f;
  if (w == 0){
    #pragma unroll
    for (int k = 0; k < 8; ++k) sva += v_att[l + 64 * k];
    sva += __shfl_xor(sva, 1);  sva += __shfl_xor(sva, 2);
    sva += __shfl_xor(sva, 4);  sva += __shfl_xor(sva, 8);
    sva += __shfl_xor(sva, 16); sva += __shfl_xor(sva, 32);
  }

  // A-fragment loads don't depend on LDS: hoist first k-step above the barrier.
  const unsigned short* Wbase = Wb + (w * 4 * 16 + l16) * H_ + quad * 8;
  bf16x8 a0[4], a1[4], b0[4], b1[4];
  #pragma unroll
  for (int ti = 0; ti < 4; ++ti)
    a0[ti] = *(const bf16x8*)(Wbase + ti * 16 * H_ + 0);

  __syncthreads();

  float tacc[4] = {0.f, 0.f, 0.f, 0.f};   // sum_h v[h]*r[h][s]
  {
    floatx4 acc[4][4];
    #pragma unroll
    for (int ti = 0; ti < 4; ++ti)
      #pragma unroll
      for (int ss = 0; ss < 4; ++ss){
        floatx4 z4 = {0.f, 0.f, 0.f, 0.f};
        acc[ti][ss] = z4;
      }

    #pragma unroll
    for (int ss = 0; ss < 4; ++ss)
      b0[ss] = *(const bf16x8*)(&sm.Bs[(ss * 16 + l16) * 512 + swz(l16, quad) * 8]);

    // 2-deep pipelined k-loop: prefetch k+32 while MFMA'ing k.
    #pragma unroll
    for (int k0 = 0; k0 < H_; k0 += 64){
      const int kA = k0 + 32;
      #pragma unroll
      for (int ti = 0; ti < 4; ++ti)
        a1[ti] = *(const bf16x8*)(Wbase + ti * 16 * H_ + kA);
      #pragma unroll
      for (int ss = 0; ss < 4; ++ss)
        b1[ss] = *(const bf16x8*)(&sm.Bs[(ss * 16 + l16) * 512 + swz(l16, (kA >> 3) + quad) * 8]);
      #pragma unroll
      for (int ti = 0; ti < 4; ++ti)
        #pragma unroll
        for (int ss = 0; ss < 4; ++ss)
          acc[ti][ss] = __builtin_amdgcn_mfma_f32_16x16x32_bf16(a0[ti], b0[ss], acc[ti][ss], 0, 0, 0);

      if (k0 + 64 < H_){
        const int kB = k0 + 64;
        #pragma unroll
        for (int ti = 0; ti < 4; ++ti)
          a0[ti] = *(const bf16x8*)(Wbase + ti * 16 * H_ + kB);
        #pragma unroll
        for (int ss = 0; ss < 4; ++ss)
          b0[ss] = *(const bf16x8*)(&sm.Bs[(ss * 16 + l16) * 512 + swz(l16, (kB >> 3) + quad) * 8]);
      }
      #pragma unroll
      for (int ti = 0; ti < 4; ++ti)
        #pragma unroll
        for (int ss = 0; ss < 4; ++ss)
          acc[ti][ss] = __builtin_amdgcn_mfma_f32_16x16x32_bf16(a1[ti], b1[ss], acc[ti][ss], 0, 0, 0);
    }

    // t[s] = SVA - 2*sum_h v[h]*r ; accumulate sum v*r (4-op tanh).
    // C layout col=l16 (s), row=quad*4+r.
    #pragma unroll
    for (int ti = 0; ti < 4; ++ti){
      const int hbase = (w * 4 + ti) * 16 + quad * 4;
      #pragma unroll
      for (int r = 0; r < 4; ++r){
        float va = vatt[hbase + r];
        #pragma unroll
        for (int ss = 0; ss < 4; ++ss)
          tacc[ss] = fmaf(va, tanh_r(acc[ti][ss][r] * KT_TANH), tacc[ss]);
      }
    }
  }

  #pragma unroll
  for (int ss = 0; ss < 4; ++ss){
    tacc[ss] += __shfl_xor(tacc[ss], 16);
    tacc[ss] += __shfl_xor(tacc[ss], 32);
  }
  if (l < 16){
    #pragma unroll
    for (int ss = 0; ss < 4; ++ss) twav[w][ss * 16 + l] = tacc[ss];
  }
  __syncthreads();

  // Single-wave softmax: lane s of wave 0 owns ts[s]; shuffle max+sum.
  const int pidx = b * NP + p;
  if (w == 0){
    float a = 0.f;
    #pragma unroll
    for (int ww = 0; ww < 8; ++ww) a += twav[ww][l];
    float t = sva - 2.f * a;
    float m = t;
    m = fmaxf(m, __shfl_xor(m, 1));  m = fmaxf(m, __shfl_xor(m, 2));
    m = fmaxf(m, __shfl_xor(m, 4));  m = fmaxf(m, __shfl_xor(m, 8));
    m = fmaxf(m, __shfl_xor(m, 16)); m = fmaxf(m, __shfl_xor(m, 32));
    float e = __expf(t - m);
    es[l] = e;
    float z = e;
    z += __shfl_xor(z, 1);  z += __shfl_xor(z, 2);
    z += __shfl_xor(z, 4);  z += __shfl_xor(z, 8);
    z += __shfl_xor(z, 16); z += __shfl_xor(z, 32);
    if (l == 0){ part_m[pidx] = m; part_z[pidx] = z; }
  }
  __syncthreads();

  // Partial (unnormalized) context:
  // phase R: wave w consumes rows [w*8, w*8+8), lane l -> chunk l (b128,
  //          conflict-free row readback), accumulating 8 h-values in regs.
  float a8[8] = {0.f,0.f,0.f,0.f,0.f,0.f,0.f,0.f};
  #pragma unroll
  for (int j = 0; j < 8; ++j){
    const int s = w * 8 + j;
    const float ez = es[s];                       // wave-uniform broadcast
    bf16x8 v = *(const bf16x8*)(&sm.Bs[s * 512 + swz(s, l) * 8]);
    #pragma unroll
    for (int e = 0; e < 8; ++e)
      a8[e] = fmaf(ez, bf2f((unsigned short)v[e]), a8[e]);
  }
  __syncthreads();               // all Bs reads done -> safe to alias
  // phase W: interleaved lo/hi (lane stride 16B -> all 32 banks, conflict-free)
  {
    floatx4 lo = {a8[0], a8[1], a8[2], a8[3]};
    floatx4 hi = {a8[4], a8[5], a8[6], a8[7]};
    *(floatx4*)(&sm.pctx[w * H_ + l * 4])       = lo;   // h = 8l..8l+3
    *(floatx4*)(&sm.pctx[w * H_ + 256 + l * 4]) = hi;   // h = 8l+4..8l+7
  }
  __syncthreads();
  // phase F: h = tid; idx = (h>>3)*4 + (h&3) + ((h&4)<<6); 2-way access = free
  {
    const int idx = ((tid >> 3) << 2) + (tid & 3) + ((tid & 4) << 6);
    float a = 0.f;
    #pragma unroll
    for (int ww = 0; ww < 8; ++ww) a += sm.pctx[ww * H_ + idx];
    part_ctx[(size_t)pidx * H_ + tid] = a;
  }
}

// ---------------- k2: combine partials -> context -> 2-layer MLP ------------
__global__ __launch_bounds__(256) void k_mlp(
    const float* __restrict__ part_m, const float* __restrict__ part_z,
    const float* __restrict__ part_ctx,
    const float* __restrict__ fc1_w, const float* __restrict__ fc1_b,
    const float* __restrict__ fc2_w, const float* __restrict__ fc2_b,
    float* __restrict__ out2)
{
  __shared__ float ctx[H_];
  __shared__ float h1[H_];
  __shared__ float wp[NP];
  const int b = blockIdx.x, tid = threadIdx.x;

  float m = -1e30f;
  for (int pp = 0; pp < NP; ++pp) m = fmaxf(m, part_m[b * NP + pp]);
  if (tid < NP) wp[tid] = __expf(part_m[b * NP + tid] - m);
  __syncthreads();
  float z = 0.f;
  for (int pp = 0; pp < NP; ++pp) z += wp[pp] * part_z[b * NP + pp];
  float invz = 1.f / z;

  for (int h = tid; h < H_; h += 256){
    float a = 0.f;
    for (int pp = 0; pp < NP; ++pp) a += wp[pp] * part_ctx[(size_t)(b * NP + pp) * H_ + h];
    ctx[h] = a * invz;
  }
  __syncthreads();

  for (int i = tid; i < H_; i += 256){
    const float4* row = (const float4*)(fc1_w + (size_t)i * H_);
    float4 s4 = {0.f, 0.f, 0.f, 0.f};
    for (int j = 0; j < H_ / 4; ++j){
      float4 wv = row[j];
      s4.x += wv.x * ctx[4 * j];     s4.y += wv.y * ctx[4 * j + 1];
      s4.z += wv.z * ctx[4 * j + 2]; s4.w += wv.w * ctx[4 * j + 3];
    }
    h1[i] = fmaxf(fc1_b[i] + s4.x + s4.y + s4.z + s4.w, 0.f);
  }
  __syncthreads();

  for (int i = tid; i < H_; i += 256){
    const float4* row = (const float4*)(fc2_w + (size_t)i * H_);
    float4 s4 = {0.f, 0.f, 0.f, 0.f};
    for (int j = 0; j < H_ / 4; ++j){
      float4 wv = row[j];
      s4.x += wv.x * h1[4 * j];     s4.y += wv.y * h1[4 * j + 1];
      s4.z += wv.z * h1[4 * j + 2]; s4.w += wv.w * h1[4 * j + 3];
    }
    out2[(size_t)b * H_ + i] = fmaxf(fc2_b[i] + s4.x + s4.y + s4.z + s4.w, 0.f);
  }
}

// ---------------- k_probs: fp32 hidden, lane-owns-s, no cross-lane reduce ---
// probs[b,s] = SVP - 2 * sum_h vp[h]*rcp(exp2(KT*hid + KT*o[h])+1)
__global__ __launch_bounds__(256) void k_probs(
    const float* __restrict__ hidden, const float* __restrict__ v_ptr,
    const float* __restrict__ out2, float* __restrict__ probs)
{
  __shared__ float vp[H_], ko[H_];
  __shared__ float svp_sh;
  const int b = blockIdx.y, c = blockIdx.x, tid = threadIdx.x;
  vp[tid]       = v_ptr[tid];
  vp[tid + 256] = v_ptr[tid + 256];
  ko[tid]       = KT_TANH * out2[(size_t)b * H_ + tid];
  ko[tid + 256] = KT_TANH * out2[(size_t)b * H_ + tid + 256];
  __syncthreads();
  if (tid < 64){
    float sv = 0.f;
    #pragma unroll
    for (int k = 0; k < 8; ++k) sv += vp[tid + 64 * k];
    sv += __shfl_xor(sv, 1);  sv += __shfl_xor(sv, 2);
    sv += __shfl_xor(sv, 4);  sv += __shfl_xor(sv, 8);
    sv += __shfl_xor(sv, 16); sv += __shfl_xor(sv, 32);
    if (tid == 0) svp_sh = sv;
  }
  __syncthreads();

  const int s = c * 512 + tid * 2;
  const float* base = hidden + (size_t)b * H_ * S_ + s;
  float a0 = 0.f, a1 = 0.f;
  const float kt = KT_TANH;
  #pragma unroll 16
  for (int h = 0; h < H_; ++h){
    float2 hv = *(const float2*)(base + (size_t)h * S_);
    float wv = vp[h], o = ko[h];
    a0 = fmaf(wv, tanh_r(fmaf(kt, hv.x, o)), a0);
    a1 = fmaf(wv, tanh_r(fmaf(kt, hv.y, o)), a1);
  }
  float svp = svp_sh;
  float2 r2 = { svp - 2.f * a0, svp - 2.f * a1 };
  *(float2*)(probs + (size_t)b * S_ + s) = r2;
}

// ---------------- launcher ----------------
extern "C" void kernel_launch(void* const* d_in, const int* in_sizes, int n_in,
                              void* d_out, int out_size, void* d_ws, size_t ws_size,
                              hipStream_t stream)
{
  const float* hidden = (const float*)d_in[0];
  const float* v_att  = (const float*)d_in[1];
  const float* W_att  = (const float*)d_in[2];
  const float* v_ptr  = (const float*)d_in[3];
  const float* fc1_w  = (const float*)d_in[4];
  const float* fc1_b  = (const float*)d_in[5];
  const float* fc2_w  = (const float*)d_in[6];
  const float* fc2_b  = (const float*)d_in[7];
  float* probs = (float*)d_out;

  char* ws = (char*)d_ws;
  unsigned short* Wb = (unsigned short*)ws;                        // 512 KiB
  float* part_m   = (float*)(ws + (512u<<10));                     // 16 KiB
  float* part_z   = (float*)(ws + (512u<<10) + (16u<<10));         // 16 KiB
  float* part_ctx = (float*)(ws + (512u<<10) + (32u<<10));         // 8 MiB
  float* out2     = (float*)(ws + (512u<<10) + (32u<<10) + (8u<<20)); // 256 KiB

  hipLaunchKernelGGL(k_convW, dim3(256), dim3(256), 0, stream, W_att, Wb);
  hipLaunchKernelGGL(k_pass1, dim3(B_ * NP), dim3(512), 0, stream,
                     hidden, v_att, Wb, part_m, part_z, part_ctx);
  hipLaunchKernelGGL(k_mlp, dim3(B_), dim3(256), 0, stream,
                     part_m, part_z, part_ctx, fc1_w, fc1_b, fc2_w, fc2_b, out2);
  hipLaunchKernelGGL(k_probs, dim3(S_ / 512, B_), dim3(256), 0, stream,
                     hidden, v_ptr, out2, probs);
}

// Round 3
// 1040.548 us; speedup vs baseline: 1.0404x; 1.0404x over previous
//
#include <hip/hip_runtime.h>
#include <hip/hip_bf16.h>

#define B_ 128
#define H_ 512
#define S_ 2048
#define ST 64          // s-tile per pass-1 block
#define NP (S_/ST)     // 32 partials per batch

typedef short  bf16x8  __attribute__((ext_vector_type(8)));
typedef float  floatx4 __attribute__((ext_vector_type(4)));
typedef short  short4v __attribute__((ext_vector_type(4)));

// 2*log2(e): tanh(x) = 1 - 2*rcp(exp2(KT*x)+1)  (saturates correctly at +-inf)
#define KT_TANH 2.8853900817779268f

__device__ __forceinline__ unsigned short f2bf(float f){
  unsigned u = __float_as_uint(f);
  unsigned r = (u + 0x7fffu + ((u >> 16) & 1u)) >> 16;   // RNE
  return (unsigned short)r;
}
__device__ __forceinline__ float bf2f(unsigned short h){
  return __uint_as_float(((unsigned)h) << 16);
}
// r = rcp(exp2(a)+1) ; tanh = 1 - 2r
__device__ __forceinline__ float tanh_r(float a){
  float e = __builtin_amdgcn_exp2f(a);
  return __builtin_amdgcn_rcpf(e + 1.f);
}
// XOR swizzle: row-stride 512 elems (no pad); 16B chunk c of row s lives at
// phys = (c & 56) | ((c ^ s) & 7). Conflict-free for row-writes, frag-reads,
// and full-row readback (bijective in c for fixed s).
__device__ __forceinline__ int swz(int s, int c){
  return (c & 56) | ((c ^ s) & 7);
}

// ---------------- k0: W_att fp32 -> bf16 ----------------
__global__ __launch_bounds__(256) void k_convW(const float* __restrict__ W,
                                               unsigned short* __restrict__ Wb){
  int i = (blockIdx.x * 256 + threadIdx.x) * 4;
  float4 v = *(const float4*)(W + i);
  short4v o;
  o[0] = (short)f2bf(v.x); o[1] = (short)f2bf(v.y);
  o[2] = (short)f2bf(v.z); o[3] = (short)f2bf(v.w);
  *(short4v*)(Wb + i) = o;
}

// ---------------- k_trans: 512x512 fp32 transpose (fc weights) -------------
// dst[a][b] = src[b][a]; blockIdx.z picks the matrix.
__global__ __launch_bounds__(256) void k_trans(const float* __restrict__ src0,
                                               float* __restrict__ dst0,
                                               const float* __restrict__ src1,
                                               float* __restrict__ dst1){
  __shared__ float t[32][33];
  const float* src = blockIdx.z ? src1 : src0;
  float*       dst = blockIdx.z ? dst1 : dst0;
  const int bx = blockIdx.x * 32, by = blockIdx.y * 32;
  const int x = threadIdx.x & 31, y = threadIdx.x >> 5;   // 32 x 8
  #pragma unroll
  for (int r = 0; r < 32; r += 8)
    t[y + r][x] = src[(size_t)(by + y + r) * H_ + bx + x];
  __syncthreads();
  #pragma unroll
  for (int r = 0; r < 32; r += 8)
    dst[(size_t)(bx + y + r) * H_ + by + x] = t[x][y + r];
}

// ---------------- k_pass1: stage + scores GEMM + tanh.v + partial softmax ---
// grid = B*NP blocks of 512 (8 waves). Wave w owns h-rows [w*64, w*64+64).
// hT (bf16 [b,s,h]) is written during the phase-R readback (zero extra LDS).
template<int WRITE_HT>
__global__ __launch_bounds__(512, 4) void k_pass1(
    const float* __restrict__ hidden, const float* __restrict__ v_att,
    const unsigned short* __restrict__ Wb,
    float* __restrict__ part_m, float* __restrict__ part_z,
    float* __restrict__ part_ctx, unsigned short* __restrict__ hT)
{
  // pctx (16 KiB fp32 cross-wave ctx reduce) aliases Bs (barrier-separated).
  union __align__(16) SMem {
    unsigned short Bs[ST * 512];   // 64 KiB, swizzled bf16 [s][k]
    float pctx[8 * H_];            // 16 KiB
  };
  __shared__ SMem sm;
  __shared__ float vatt[H_];
  __shared__ float twav[8][ST];
  __shared__ float es[ST];

  const int tid = threadIdx.x;
  const int w = tid >> 6, l = tid & 63;
  const int p = blockIdx.x & (NP - 1);
  const int b = blockIdx.x >> 5;          // NP == 32
  const int s0 = p * ST;

  vatt[tid] = v_att[tid];

  // Stage hidden[b, :, s0:s0+64] -> bf16 LDS [s][k] (swizzled).
  // Thread: row s=l, 8 chunks c = w + it*8; chunk = 8 h, stride-S gather
  // (coalesced 256B/wave per h-row). Nontemporal: keep Wb L2-hot.
  {
    const float* src0 = hidden + ((size_t)b * H_) * S_ + s0 + l;
    #pragma unroll
    for (int it = 0; it < 8; ++it){
      const int c = w + it * 8;
      const float* src = src0 + (size_t)(c * 8) * S_;
      bf16x8 pk;
      #pragma unroll
      for (int j = 0; j < 8; ++j)
        pk[j] = (short)f2bf(__builtin_nontemporal_load(src + (size_t)j * S_));
      *(bf16x8*)(&sm.Bs[l * 512 + swz(l, c) * 8]) = pk;
    }
  }

  // SVA = sum_h v_att[h]; wave-0 register reduce.
  float sva = 0.f;
  if (w == 0){
    #pragma unroll
    for (int k = 0; k < 8; ++k) sva += v_att[l + 64 * k];
    sva += __shfl_xor(sva, 1);  sva += __shfl_xor(sva, 2);
    sva += __shfl_xor(sva, 4);  sva += __shfl_xor(sva, 8);
    sva += __shfl_xor(sva, 16); sva += __shfl_xor(sva, 32);
  }
  __syncthreads();

  const int quad = l >> 4, l16 = l & 15;
  float tacc[4] = {0.f, 0.f, 0.f, 0.f};   // sum_h v[h]*r[h][s]

  {
    floatx4 acc[4][4];
    #pragma unroll
    for (int ti = 0; ti < 4; ++ti)
      #pragma unroll
      for (int ss = 0; ss < 4; ++ss){
        floatx4 z4 = {0.f, 0.f, 0.f, 0.f};
        acc[ti][ss] = z4;
      }

    // Simple k-loop; compiler schedules loads/MFMA (R2's manual pipeline lost).
    for (int k0 = 0; k0 < H_; k0 += 32){
      bf16x8 a[4];
      #pragma unroll
      for (int ti = 0; ti < 4; ++ti)
        a[ti] = *(const bf16x8*)(Wb + ((w * 4 + ti) * 16 + l16) * H_ + k0 + quad * 8);
      bf16x8 bb[4];
      #pragma unroll
      for (int ss = 0; ss < 4; ++ss){
        const int c = (k0 >> 3) + quad;
        bb[ss] = *(const bf16x8*)(&sm.Bs[(ss * 16 + l16) * 512 + swz(l16, c) * 8]);
      }
      #pragma unroll
      for (int ti = 0; ti < 4; ++ti)
        #pragma unroll
        for (int ss = 0; ss < 4; ++ss)
          acc[ti][ss] = __builtin_amdgcn_mfma_f32_16x16x32_bf16(a[ti], bb[ss], acc[ti][ss], 0, 0, 0);
    }

    // t[s] = SVA - 2*sum_h v[h]*r ; accumulate sum v*r (4-op tanh).
    // C layout col=l16 (s), row=quad*4+r.
    #pragma unroll
    for (int ti = 0; ti < 4; ++ti){
      const int hbase = (w * 4 + ti) * 16 + quad * 4;
      #pragma unroll
      for (int r = 0; r < 4; ++r){
        float va = vatt[hbase + r];
        #pragma unroll
        for (int ss = 0; ss < 4; ++ss)
          tacc[ss] = fmaf(va, tanh_r(acc[ti][ss][r] * KT_TANH), tacc[ss]);
      }
    }
  }

  #pragma unroll
  for (int ss = 0; ss < 4; ++ss){
    tacc[ss] += __shfl_xor(tacc[ss], 16);
    tacc[ss] += __shfl_xor(tacc[ss], 32);
  }
  if (l < 16){
    #pragma unroll
    for (int ss = 0; ss < 4; ++ss) twav[w][ss * 16 + l] = tacc[ss];
  }
  __syncthreads();

  // Single-wave softmax: lane s of wave 0; shuffle max+sum.
  const int pidx = b * NP + p;
  if (w == 0){
    float a = 0.f;
    #pragma unroll
    for (int ww = 0; ww < 8; ++ww) a += twav[ww][l];
    float t = sva - 2.f * a;
    float m = t;
    m = fmaxf(m, __shfl_xor(m, 1));  m = fmaxf(m, __shfl_xor(m, 2));
    m = fmaxf(m, __shfl_xor(m, 4));  m = fmaxf(m, __shfl_xor(m, 8));
    m = fmaxf(m, __shfl_xor(m, 16)); m = fmaxf(m, __shfl_xor(m, 32));
    float e = __expf(t - m);
    es[l] = e;
    float z = e;
    z += __shfl_xor(z, 1);  z += __shfl_xor(z, 2);
    z += __shfl_xor(z, 4);  z += __shfl_xor(z, 8);
    z += __shfl_xor(z, 16); z += __shfl_xor(z, 32);
    if (l == 0){ part_m[pidx] = m; part_z[pidx] = z; }
  }
  __syncthreads();

  // phase R: wave w rows [w*8, w*8+8), lane l -> chunk l (b128 conflict-free).
  // Fused hT writeback: same data, 8 nontemporal 16B stores.
  float a8[8] = {0.f,0.f,0.f,0.f,0.f,0.f,0.f,0.f};
  #pragma unroll
  for (int j = 0; j < 8; ++j){
    const int s = w * 8 + j;
    const float ez = es[s];                       // wave-uniform broadcast
    bf16x8 v = *(const bf16x8*)(&sm.Bs[s * 512 + swz(s, l) * 8]);
    if (WRITE_HT)
      __builtin_nontemporal_store(v,
          (bf16x8*)(hT + ((size_t)(b * S_) + s0 + s) * H_ + l * 8));
    #pragma unroll
    for (int e = 0; e < 8; ++e)
      a8[e] = fmaf(ez, bf2f((unsigned short)v[e]), a8[e]);
  }
  __syncthreads();               // all Bs reads done -> safe to alias
  // phase W: interleaved lo/hi (lane stride 16B -> all 32 banks)
  {
    floatx4 lo = {a8[0], a8[1], a8[2], a8[3]};
    floatx4 hi = {a8[4], a8[5], a8[6], a8[7]};
    *(floatx4*)(&sm.pctx[w * H_ + l * 4])       = lo;   // h = 8l..8l+3
    *(floatx4*)(&sm.pctx[w * H_ + 256 + l * 4]) = hi;   // h = 8l+4..8l+7
  }
  __syncthreads();
  // phase F: h = tid; idx = (h>>3)*4 + (h&3) + ((h&4)<<6); 2-way = free
  {
    const int idx = ((tid >> 3) << 2) + (tid & 3) + ((tid & 4) << 6);
    float a = 0.f;
    #pragma unroll
    for (int ww = 0; ww < 8; ++ww) a += sm.pctx[ww * H_ + idx];
    part_ctx[(size_t)pidx * H_ + tid] = a;
  }
}

// ---------------- k_fc1: combine partials -> ctx -> relu(W1 ctx + b1) -------
// grid (2, B_): blockIdx.y = b, blockIdx.x = i-half. Transposed weights:
// lane-consecutive i => coalesced 256B column reads.
__global__ __launch_bounds__(256) void k_fc1(
    const float* __restrict__ part_m, const float* __restrict__ part_z,
    const float* __restrict__ part_ctx,
    const float* __restrict__ w1t, const float* __restrict__ fc1_b,
    float* __restrict__ h1out)
{
  __shared__ float ctxs[H_];
  __shared__ float wp[NP];
  const int b = blockIdx.y, ih = blockIdx.x, tid = threadIdx.x;

  float m = -1e30f;
  for (int pp = 0; pp < NP; ++pp) m = fmaxf(m, part_m[b * NP + pp]);
  if (tid < NP) wp[tid] = __expf(part_m[b * NP + tid] - m);
  __syncthreads();
  float z = 0.f;
  for (int pp = 0; pp < NP; ++pp) z += wp[pp] * part_z[b * NP + pp];
  const float invz = 1.f / z;

  #pragma unroll
  for (int h = tid; h < H_; h += 256){
    float a = 0.f;
    for (int pp = 0; pp < NP; ++pp)
      a += wp[pp] * part_ctx[(size_t)(b * NP + pp) * H_ + h];
    ctxs[h] = a * invz;
  }
  __syncthreads();

  const int i = ih * 256 + tid;
  const float* col = w1t + i;                 // w1t[k][i], stride H_
  float acc = fc1_b[i];
  #pragma unroll 8
  for (int k = 0; k < H_; ++k)
    acc = fmaf(col[(size_t)k * H_], ctxs[k], acc);
  h1out[(size_t)b * H_ + i] = fmaxf(acc, 0.f);
}

// ---------------- k_fc2: out2 = relu(W2 h1 + b2) ---------------------------
__global__ __launch_bounds__(256) void k_fc2(
    const float* __restrict__ h1, const float* __restrict__ w2t,
    const float* __restrict__ fc2_b, float* __restrict__ out2)
{
  __shared__ float h1s[H_];
  const int b = blockIdx.y, ih = blockIdx.x, tid = threadIdx.x;
  h1s[tid]       = h1[(size_t)b * H_ + tid];
  h1s[tid + 256] = h1[(size_t)b * H_ + tid + 256];
  __syncthreads();

  const int i = ih * 256 + tid;
  const float* col = w2t + i;
  float acc = fc2_b[i];
  #pragma unroll 8
  for (int k = 0; k < H_; ++k)
    acc = fmaf(col[(size_t)k * H_], h1s[k], acc);
  out2[(size_t)b * H_ + i] = fmaxf(acc, 0.f);
}

// ---------------- k_probs_hT: bf16 hT reads, per-row shuffle reduce --------
// probs[b,s] = SVP - 2 * sum_h vp[h]*rcp(exp2(KT*hid + KT*o[h])+1)
__global__ __launch_bounds__(256) void k_probs_hT(
    const unsigned short* __restrict__ hT, const float* __restrict__ v_ptr,
    const float* __restrict__ out2, float* __restrict__ probs)
{
  const int tid = threadIdx.x, w = tid >> 6, l = tid & 63;
  const int b = blockIdx.y, s0 = blockIdx.x * 64;

  float vp[8], ko[8];
  {
    float4 a = *(const float4*)(v_ptr + l * 8);
    float4 c = *(const float4*)(v_ptr + l * 8 + 4);
    vp[0]=a.x; vp[1]=a.y; vp[2]=a.z; vp[3]=a.w;
    vp[4]=c.x; vp[5]=c.y; vp[6]=c.z; vp[7]=c.w;
    float4 d = *(const float4*)(out2 + (size_t)b * H_ + l * 8);
    float4 e = *(const float4*)(out2 + (size_t)b * H_ + l * 8 + 4);
    ko[0]=KT_TANH*d.x; ko[1]=KT_TANH*d.y; ko[2]=KT_TANH*d.z; ko[3]=KT_TANH*d.w;
    ko[4]=KT_TANH*e.x; ko[5]=KT_TANH*e.y; ko[6]=KT_TANH*e.z; ko[7]=KT_TANH*e.w;
  }
  // SVP = sum_h vp[h] across the wave
  float svp = vp[0]+vp[1]+vp[2]+vp[3]+vp[4]+vp[5]+vp[6]+vp[7];
  svp += __shfl_xor(svp, 1);  svp += __shfl_xor(svp, 2);
  svp += __shfl_xor(svp, 4);  svp += __shfl_xor(svp, 8);
  svp += __shfl_xor(svp, 16); svp += __shfl_xor(svp, 32);

  const unsigned short* base = hT + (size_t)(b * S_ + s0) * H_ + l * 8;
  const float kt = KT_TANH;
  #pragma unroll 2
  for (int i = 0; i < 16; ++i){
    const int s = w * 16 + i;
    bf16x8 hv = __builtin_nontemporal_load((const bf16x8*)(base + (size_t)s * H_));
    float acc = 0.f;
    #pragma unroll
    for (int j = 0; j < 8; ++j)
      acc = fmaf(vp[j], tanh_r(fmaf(kt, bf2f((unsigned short)hv[j]), ko[j])), acc);
    acc += __shfl_xor(acc, 1);  acc += __shfl_xor(acc, 2);
    acc += __shfl_xor(acc, 4);  acc += __shfl_xor(acc, 8);
    acc += __shfl_xor(acc, 16); acc += __shfl_xor(acc, 32);
    if (l == 0) probs[(size_t)b * S_ + s0 + s] = svp - 2.f * acc;
  }
}

// ---------------- k_probs_f32: fallback (no hT workspace) -------------------
__global__ __launch_bounds__(256) void k_probs_f32(
    const float* __restrict__ hidden, const float* __restrict__ v_ptr,
    const float* __restrict__ out2, float* __restrict__ probs)
{
  __shared__ float vp[H_], ko[H_];
  __shared__ float svp_sh;
  const int b = blockIdx.y, c = blockIdx.x, tid = threadIdx.x;
  vp[tid]       = v_ptr[tid];
  vp[tid + 256] = v_ptr[tid + 256];
  ko[tid]       = KT_TANH * out2[(size_t)b * H_ + tid];
  ko[tid + 256] = KT_TANH * out2[(size_t)b * H_ + tid + 256];
  __syncthreads();
  if (tid < 64){
    float sv = 0.f;
    #pragma unroll
    for (int k = 0; k < 8; ++k) sv += vp[tid + 64 * k];
    sv += __shfl_xor(sv, 1);  sv += __shfl_xor(sv, 2);
    sv += __shfl_xor(sv, 4);  sv += __shfl_xor(sv, 8);
    sv += __shfl_xor(sv, 16); sv += __shfl_xor(sv, 32);
    if (tid == 0) svp_sh = sv;
  }
  __syncthreads();

  const int s = c * 512 + tid * 2;
  const float* base = hidden + (size_t)b * H_ * S_ + s;
  float a0 = 0.f, a1 = 0.f;
  const float kt = KT_TANH;
  #pragma unroll 16
  for (int h = 0; h < H_; ++h){
    float2 hv = *(const float2*)(base + (size_t)h * S_);
    float wv = vp[h], o = ko[h];
    a0 = fmaf(wv, tanh_r(fmaf(kt, hv.x, o)), a0);
    a1 = fmaf(wv, tanh_r(fmaf(kt, hv.y, o)), a1);
  }
  float svp = svp_sh;
  float2 r2 = { svp - 2.f * a0, svp - 2.f * a1 };
  *(float2*)(probs + (size_t)b * S_ + s) = r2;
}

// ---------------- launcher ----------------
extern "C" void kernel_launch(void* const* d_in, const int* in_sizes, int n_in,
                              void* d_out, int out_size, void* d_ws, size_t ws_size,
                              hipStream_t stream)
{
  const float* hidden = (const float*)d_in[0];
  const float* v_att  = (const float*)d_in[1];
  const float* W_att  = (const float*)d_in[2];
  const float* v_ptr  = (const float*)d_in[3];
  const float* fc1_w  = (const float*)d_in[4];
  const float* fc1_b  = (const float*)d_in[5];
  const float* fc2_w  = (const float*)d_in[6];
  const float* fc2_b  = (const float*)d_in[7];
  float* probs = (float*)d_out;

  char* ws = (char*)d_ws;
  unsigned short* Wb = (unsigned short*)ws;                        // 512 KiB @0
  float* part_m   = (float*)(ws + (512u<<10));                     // 16 KiB
  float* part_z   = (float*)(ws + (528u<<10));                     // 16 KiB
  float* part_ctx = (float*)(ws + (1u<<20));                       // 8 MiB @1M
  float* out2     = (float*)(ws + (9u<<20));                       // 256 KiB
  float* h1buf    = (float*)(ws + (9u<<20) + (256u<<10));          // 256 KiB
  float* w1t      = (float*)(ws + (10u<<20));                      // 1 MiB
  float* w2t      = (float*)(ws + (11u<<20));                      // 1 MiB
  unsigned short* hT = (unsigned short*)(ws + (16u<<20));          // 256 MiB

  const size_t need_full = (16u<<20) + ((size_t)B_ * S_ * H_ * 2);

  hipLaunchKernelGGL(k_convW, dim3(256), dim3(256), 0, stream, W_att, Wb);
  hipLaunchKernelGGL(k_trans, dim3(16, 16, 2), dim3(256), 0, stream,
                     fc1_w, w1t, fc2_w, w2t);

  if (ws_size >= need_full){
    hipLaunchKernelGGL(k_pass1<1>, dim3(B_ * NP), dim3(512), 0, stream,
                       hidden, v_att, Wb, part_m, part_z, part_ctx, hT);
  } else {
    hipLaunchKernelGGL(k_pass1<0>, dim3(B_ * NP), dim3(512), 0, stream,
                       hidden, v_att, Wb, part_m, part_z, part_ctx, (unsigned short*)Wb);
  }

  hipLaunchKernelGGL(k_fc1, dim3(2, B_), dim3(256), 0, stream,
                     part_m, part_z, part_ctx, w1t, fc1_b, h1buf);
  hipLaunchKernelGGL(k_fc2, dim3(2, B_), dim3(256), 0, stream,
                     h1buf, w2t, fc2_b, out2);

  if (ws_size >= need_full){
    hipLaunchKernelGGL(k_probs_hT, dim3(S_ / 64, B_), dim3(256), 0, stream,
                       hT, v_ptr, out2, probs);
  } else {
    hipLaunchKernelGGL(k_probs_f32, dim3(S_ / 512, B_), dim3(256), 0, stream,
                       hidden, v_ptr, out2, probs);
  }
}